// Round 4
// baseline (249.985 us; speedup 1.0000x reference)
//
#include <hip/hip_runtime.h>
#include <hip/hip_bf16.h>
#include <math.h>

#define Bn 4096
#define Dd 768
#define SC2 28.85390081777927f   // 20 * log2(e): logits kept in base-2 domain
#define EPSF 1e-6f
#define DG 4.8516519541e8f       // expf(20.0f): exact exp_ori diagonal

// ws layout (4-byte elements)
#define O_S      0        // 3*4096 row sums (ori_nodiag, gen, aug)
#define O_SMOA   12288    // same-masked (ori_nodiag + aug) sums
#define O_SMG    16384    // same-masked gen sums
#define ZERO_F   20480    // floats to zero (covers all atomic sums)
#define O_P      20480    // uint: total pairs (= sum cnt^2)
#define O_RM     20608    // uint2[4096]: {tg | rank<<8, rowSlotBase}
#define LIST_OFF   262144      // byte offset: LCAP uint4 pair entries {row,x0,x1,x2}
#define LCAP       (1u << 19)
#define NB_OFF     33554432    // byte offset: bf16 normalized rows on|gn|an

typedef __attribute__((ext_vector_type(8))) short sh8;
typedef __attribute__((ext_vector_type(4))) float f32x4;

#define AS1 __attribute__((address_space(1)))
#define AS3 __attribute__((address_space(3)))

static __device__ __forceinline__ void gl_lds16(const void* g, void* l) {
    __builtin_amdgcn_global_load_lds((const AS1 void*)g, (AS3 void*)l, 16, 0, 0);
}

static __device__ __forceinline__ unsigned short f2b(float f) {
    unsigned int u = __float_as_uint(f);
    unsigned int r = (u + 0x7fffu + ((u >> 16) & 1u)) >> 16;  // RNE
    return (unsigned short)r;
}

// ---- normalize rows, write bf16 ----
__global__ void norm_kernel(const float* f0, const float* f1, const float* f2, unsigned short* nb) {
    int r = blockIdx.x, m = blockIdx.y, tid = threadIdx.x;
    const float* src = (m == 0 ? f0 : (m == 1 ? f1 : f2)) + (size_t)r * Dd;
    float x0 = src[tid], x1 = src[tid + 256], x2 = src[tid + 512];
    float v = x0 * x0 + x1 * x1 + x2 * x2;
    #pragma unroll
    for (int off = 1; off < 64; off <<= 1) v += __shfl_xor(v, off);
    __shared__ float wr[4];
    if ((tid & 63) == 0) wr[tid >> 6] = v;
    __syncthreads();
    float inv = rsqrtf(wr[0] + wr[1] + wr[2] + wr[3]);
    unsigned short* dst = nb + ((size_t)m * Bn + r) * Dd;
    dst[tid] = f2b(x0 * inv);
    dst[tid + 256] = f2b(x1 * inv);
    dst[tid + 512] = f2b(x2 * inv);
}

// ---- single-block: zero accumulators + class sort (hist/scan/rank+slot) ----
__launch_bounds__(1024)
__global__ void sort_kernel(const int* tg, unsigned int* I, float* out) {
    float* F = (float*)I;
    __shared__ unsigned int h[128], pb[128], cur[128];
    int tid = threadIdx.x;
    for (int e = tid; e < ZERO_F; e += 1024) F[e] = 0.f;
    if (tid == 0) { out[0] = 0.f; out[1] = 0.f; }
    if (tid < 128) { h[tid] = 0; cur[tid] = 0; }
    __syncthreads();
    for (int e = tid; e < Bn; e += 1024) atomicAdd(&h[tg[e]], 1u);
    __syncthreads();
    if (tid < 128) pb[tid] = h[tid] * h[tid];
    __syncthreads();
    for (int s = 1; s < 128; s <<= 1) {
        unsigned int b = 0;
        if (tid < 128 && tid >= s) b = pb[tid - s];
        __syncthreads();
        if (tid < 128) pb[tid] += b;
        __syncthreads();
    }
    if (tid == 127) I[O_P] = pb[127];
    uint2* RM = (uint2*)(I + O_RM);
    for (int e = tid; e < Bn; e += 1024) {
        int c = tg[e];
        unsigned int r = atomicAdd(&cur[c], 1u);
        unsigned int n = h[c];
        RM[e] = make_uint2((unsigned)c | (r << 8), (pb[c] - n * n) + r * n);
    }
}

// ============== R17: 3-z fused + TRIPLE-BUFFER + counted vmcnt ===========
// R16 (fused, 2x __syncthreads/kt) measured 116us, MfmaUtil 27.7%: the
// syncthreads vmcnt(0) drain per K-step is the residual stall (m97 gap).
// Here: tile t in buf[t%3] (3 x 32KB = 96KB; regs already cap at 1 blk/CU
// so extra LDS is free). Per iteration kt: issue stage of t(kt+2) into
// buf[(kt+2)%3] FIRST (its readers ran at kt-1 and consumed their frags
// before the kt-1 end barrier -- consumption proof validated by R15's
// absmax 0), then frag-reads + 48 MFMA from buf[kt%3], then vmcnt(8)
// (= t(kt+1) landed, t(kt+2) still in flight; never 0 until kt=22), then
// one raw s_barrier. MFMA hides the t+1 landing; loads cross the barrier.
#define BUFS 16384   // shorts per buffer: A[0..4096) B0 B1 B2 (4096 each)

__launch_bounds__(256, 2)
__global__ void gemm_rowsum(const unsigned short* nb, char* ws) {
    float* F = (float*)ws;
    const unsigned int* I = (const unsigned int*)ws;
    const uint2* RM = (const uint2*)(I + O_RM);
    // XCD-aware swizzle (1024 % 8 == 0 -> bijective): 128 consecutive
    // tiles per XCD -> A panels L2-resident.
    int bid = blockIdx.x;
    int sw = (bid & 7) * 128 + (bid >> 3);
    int m0 = (sw >> 5) * 128, n0 = (sw & 31) * 128;
    int tid = threadIdx.x, lane = tid & 63, wave = tid >> 6;
    int wm = (wave >> 1) * 64, wn = (wave & 1) * 64;   // 2x2 waves, 64x64/wave/z
    int lid = lane & 15, q = lane >> 4;
    __shared__ __align__(16) unsigned short L[3 * BUFS];   // 96 KB

    // staging: thread -> (row = tid>>2, chunk = tid&3); rows 0..63 load0,
    // 64..127 load1 ((row+64)>>1 & 3 unchanged). LDS linear dest,
    // source chunk pre-swizzled (both-sides-or-neither rule).
    int row0 = tid >> 2, ch = tid & 3;
    int cs = (ch ^ ((row0 >> 1) & 3)) * 8;
    const unsigned short* gA  = nb + (size_t)(m0 + row0) * Dd + cs;
    const unsigned short* gB0 = nb + (size_t)(n0 + row0) * Dd + cs;
    const unsigned short* gB1 = gB0 + (size_t)Bn * Dd;
    const unsigned short* gB2 = gB1 + (size_t)Bn * Dd;

    // frag-read swizzle: r = base + i*16 + lid -> (r>>1)&3 == (lid>>1)&3
    int cswz = (q ^ ((lid >> 1) & 3)) * 8;

    f32x4 a0[4][4] = {}, a1[4][4] = {}, a2[4][4] = {};

#define STAGE(b, kt) { \
    const unsigned short* pa  = gA  + (kt) * 32; \
    const unsigned short* pb0 = gB0 + (kt) * 32; \
    const unsigned short* pb1 = gB1 + (kt) * 32; \
    const unsigned short* pb2 = gB2 + (kt) * 32; \
    unsigned short* Lb = &L[(b) * BUFS]; \
    gl_lds16(pa, &Lb[tid * 8]); \
    gl_lds16(pa + (size_t)64 * Dd, &Lb[(tid + 256) * 8]); \
    gl_lds16(pb0, &Lb[4096 + tid * 8]); \
    gl_lds16(pb0 + (size_t)64 * Dd, &Lb[4096 + (tid + 256) * 8]); \
    gl_lds16(pb1, &Lb[8192 + tid * 8]); \
    gl_lds16(pb1 + (size_t)64 * Dd, &Lb[8192 + (tid + 256) * 8]); \
    gl_lds16(pb2, &Lb[12288 + tid * 8]); \
    gl_lds16(pb2 + (size_t)64 * Dd, &Lb[12288 + (tid + 256) * 8]); \
}
#define RAWBAR { __builtin_amdgcn_sched_barrier(0); __builtin_amdgcn_s_barrier(); __builtin_amdgcn_sched_barrier(0); }

    // prologue: stage t0 -> buf0, t1 -> buf1 (16 loads); wait t0; publish
    STAGE(0, 0);
    STAGE(1, 1);
    asm volatile("s_waitcnt vmcnt(8)" ::: "memory");
    RAWBAR;

    int bc = 0, bs = 2;
    for (int kt = 0; kt < 24; ++kt) {
        if (kt < 22) STAGE(bs, kt + 2);   // overwrites buf read at kt-1 (safe)
        const unsigned short* Lc = &L[bc * BUFS];
        sh8 af[4];
        #pragma unroll
        for (int i = 0; i < 4; ++i)
            af[i] = *(const sh8*)&Lc[(wm + i * 16 + lid) * 32 + cswz];
        {
            sh8 bf[4];
            #pragma unroll
            for (int j = 0; j < 4; ++j)
                bf[j] = *(const sh8*)&Lc[4096 + (wn + j * 16 + lid) * 32 + cswz];
            __builtin_amdgcn_s_setprio(1);
            #pragma unroll
            for (int i = 0; i < 4; ++i)
                #pragma unroll
                for (int j = 0; j < 4; ++j)
                    a0[i][j] = __builtin_amdgcn_mfma_f32_16x16x32_bf16(af[i], bf[j], a0[i][j], 0, 0, 0);
            __builtin_amdgcn_s_setprio(0);
        }
        {
            sh8 bf[4];
            #pragma unroll
            for (int j = 0; j < 4; ++j)
                bf[j] = *(const sh8*)&Lc[8192 + (wn + j * 16 + lid) * 32 + cswz];
            __builtin_amdgcn_s_setprio(1);
            #pragma unroll
            for (int i = 0; i < 4; ++i)
                #pragma unroll
                for (int j = 0; j < 4; ++j)
                    a1[i][j] = __builtin_amdgcn_mfma_f32_16x16x32_bf16(af[i], bf[j], a1[i][j], 0, 0, 0);
            __builtin_amdgcn_s_setprio(0);
        }
        {
            sh8 bf[4];
            #pragma unroll
            for (int j = 0; j < 4; ++j)
                bf[j] = *(const sh8*)&Lc[12288 + (wn + j * 16 + lid) * 32 + cswz];
            __builtin_amdgcn_s_setprio(1);
            #pragma unroll
            for (int i = 0; i < 4; ++i)
                #pragma unroll
                for (int j = 0; j < 4; ++j)
                    a2[i][j] = __builtin_amdgcn_mfma_f32_16x16x32_bf16(af[i], bf[j], a2[i][j], 0, 0, 0);
            __builtin_amdgcn_s_setprio(0);
        }
        // counted wait: t(kt+1) landed, t(kt+2) stays in flight
        if (kt < 22)       { asm volatile("s_waitcnt vmcnt(8)" ::: "memory"); }
        else if (kt == 22) { asm volatile("s_waitcnt vmcnt(0)" ::: "memory"); }
        if (kt < 23) RAWBAR;
        bc = (bc == 2) ? 0 : bc + 1;
        bs = (bs == 2) ? 0 : bs + 1;
    }

    // ---- fused epilogue: 3 row sums, 2 masked sums, single uint4 pair store
    uint2 rmc[4];
    #pragma unroll
    for (int j = 0; j < 4; ++j) rmc[j] = RM[n0 + wn + j * 16 + lid];
    uint4* Lq = (uint4*)(ws + LIST_OFF);
    #pragma unroll
    for (int i = 0; i < 4; ++i)
        #pragma unroll
        for (int reg = 0; reg < 4; ++reg) {
            int grow = m0 + wm + i * 16 + q * 4 + reg;
            uint2 rm = RM[grow];
            unsigned int trow = rm.x & 255u, rsb = rm.y;
            float rs0 = 0.f, rs1 = 0.f, rs2 = 0.f, msOA = 0.f, msG = 0.f;
            #pragma unroll
            for (int j = 0; j < 4; ++j) {
                int gcol = n0 + wn + j * 16 + lid;
                float x0 = a0[i][j][reg] * SC2;
                float x1 = a1[i][j][reg] * SC2;
                float x2 = a2[i][j][reg] * SC2;
                float e0 = exp2f(x0);
                float e1 = exp2f(x1);
                float e2 = exp2f(x2);
                if (gcol == grow) e0 = 0.f;   // ori diagonal excluded from sums
                rs0 += e0; rs1 += e1; rs2 += e2;
                if ((rmc[j].x & 255u) == trow) {
                    msOA += e0 + e2;
                    msG  += e1;
                    unsigned int slot = rsb + (rmc[j].x >> 8);
                    if (slot < LCAP)
                        Lq[slot] = make_uint4((unsigned)grow, __float_as_uint(x0),
                                              __float_as_uint(x1), __float_as_uint(x2));
                }
            }
            #pragma unroll
            for (int off = 1; off < 16; off <<= 1) {
                rs0 += __shfl_xor(rs0, off);
                rs1 += __shfl_xor(rs1, off);
                rs2 += __shfl_xor(rs2, off);
                msOA += __shfl_xor(msOA, off);
                msG  += __shfl_xor(msG, off);
            }
            if (lid == 0) {
                atomicAdd(&F[O_S + grow], rs0);
                atomicAdd(&F[O_S + Bn + grow], rs1);
                atomicAdd(&F[O_S + 2 * Bn + grow], rs2);
                atomicAdd(&F[O_SMOA + grow], msOA);
                atomicAdd(&F[O_SMG + grow], msG);
            }
        }
}

// ---- flat loss pass: inline denominators, scaled atomic into d_out ----
__launch_bounds__(256)
__global__ void loss_kernel(char* ws, float* out) {
    float* F = (float*)ws;
    const unsigned int* I = (const unsigned int*)ws;
    const uint4* L = (const uint4*)(ws + LIST_OFF);
    unsigned int n = I[O_P]; if (n > LCAP) n = LCAP;
    float a0 = 0.f, a1 = 0.f;
    unsigned int stride = gridDim.x * 256;
    for (unsigned int idx = blockIdx.x * 256 + threadIdx.x; idx < n; idx += stride) {
        uint4 en = L[idx];
        int i = (int)en.x;
        float son = F[O_S + i], sgen = F[O_S + Bn + i], saug = F[O_S + 2 * Bn + i];
        float dco = (son + saug - F[O_SMOA + i]) + sgen + EPSF;
        float dad = (sgen - F[O_SMG + i]) + saug + son + DG + EPSF;
        float eo = exp2f(__uint_as_float(en.y));
        float eg = exp2f(__uint_as_float(en.z));
        float ea = exp2f(__uint_as_float(en.w));
        a0 += -__logf(eg / (eg + dad) + EPSF);
        a1 += -__logf(eo / (eo + dco) + EPSF) - __logf(ea / (ea + dco) + EPSF);
    }
    #pragma unroll
    for (int off = 1; off < 64; off <<= 1) { a0 += __shfl_xor(a0, off); a1 += __shfl_xor(a1, off); }
    __shared__ float r0[4], r1[4];
    int tid = threadIdx.x;
    if ((tid & 63) == 0) { r0[tid >> 6] = a0; r1[tid >> 6] = a1; }
    __syncthreads();
    if (tid == 0) {
        atomicAdd(&out[0], (r0[0] + r0[1] + r0[2] + r0[3]) * (1.0f / Bn));  // ad_loss
        atomicAdd(&out[1], (r1[0] + r1[1] + r1[2] + r1[3]) * (1.0f / Bn));  // co_loss
    }
}

extern "C" void kernel_launch(void* const* d_in, const int* in_sizes, int n_in,
                              void* d_out, int out_size, void* d_ws, size_t ws_size,
                              hipStream_t stream) {
    const float* f0 = (const float*)d_in[0];
    const float* f1 = (const float*)d_in[1];
    const float* f2 = (const float*)d_in[2];
    const int* tg = (const int*)d_in[3];
    char* ws = (char*)d_ws;
    unsigned int* I = (unsigned int*)d_ws;
    unsigned short* nb = (unsigned short*)(ws + NB_OFF);
    float* out = (float*)d_out;

    norm_kernel<<<dim3(Bn, 3), 256, 0, stream>>>(f0, f1, f2, nb);
    sort_kernel<<<1, 1024, 0, stream>>>(tg, I, out);
    gemm_rowsum<<<dim3(1024), 256, 0, stream>>>(nb, ws);
    loss_kernel<<<256, 256, 0, stream>>>(ws, out);
}

// Round 5
// 211.627 us; speedup vs baseline: 1.1813x; 1.1813x over previous
//
#include <hip/hip_runtime.h>
#include <hip/hip_bf16.h>
#include <math.h>

#define Bn 4096
#define Dd 768
#define SC2 28.85390081777927f   // 20 * log2(e): logits kept in base-2 domain
#define EPSF 1e-6f
#define DG 4.8516519541e8f       // expf(20.0f): exact exp_ori diagonal

// ws layout (4-byte elements)
#define O_S      0        // 3*4096 row sums (ori_nodiag, gen, aug)
#define O_SMOA   12288    // same-masked (ori_nodiag + aug) sums
#define O_SMG    16384    // same-masked gen sums
#define ZERO_F   20480    // floats to zero (covers all atomic sums)
#define O_P      20480    // uint: total pairs (= sum cnt^2)
#define O_RM     20608    // uint2[4096]: {tg | rank<<8, rowSlotBase}
#define LIST_OFF   262144      // byte offset: LCAP uint4 pair entries {row,x0,x1,x2}
#define LCAP       (1u << 19)
#define NB_OFF     33554432    // byte offset: bf16 normalized rows on|gn|an

typedef __attribute__((ext_vector_type(8))) short sh8;
typedef __attribute__((ext_vector_type(4))) float f32x4;

#define AS1 __attribute__((address_space(1)))
#define AS3 __attribute__((address_space(3)))

static __device__ __forceinline__ void gl_lds16(const void* g, void* l) {
    __builtin_amdgcn_global_load_lds((const AS1 void*)g, (AS3 void*)l, 16, 0, 0);
}

static __device__ __forceinline__ unsigned short f2b(float f) {
    unsigned int u = __float_as_uint(f);
    unsigned int r = (u + 0x7fffu + ((u >> 16) & 1u)) >> 16;  // RNE
    return (unsigned short)r;
}

// ---- normalize rows, write bf16 ----
__global__ void norm_kernel(const float* f0, const float* f1, const float* f2, unsigned short* nb) {
    int r = blockIdx.x, m = blockIdx.y, tid = threadIdx.x;
    const float* src = (m == 0 ? f0 : (m == 1 ? f1 : f2)) + (size_t)r * Dd;
    float x0 = src[tid], x1 = src[tid + 256], x2 = src[tid + 512];
    float v = x0 * x0 + x1 * x1 + x2 * x2;
    #pragma unroll
    for (int off = 1; off < 64; off <<= 1) v += __shfl_xor(v, off);
    __shared__ float wr[4];
    if ((tid & 63) == 0) wr[tid >> 6] = v;
    __syncthreads();
    float inv = rsqrtf(wr[0] + wr[1] + wr[2] + wr[3]);
    unsigned short* dst = nb + ((size_t)m * Bn + r) * Dd;
    dst[tid] = f2b(x0 * inv);
    dst[tid + 256] = f2b(x1 * inv);
    dst[tid + 512] = f2b(x2 * inv);
}

// ---- single-block: zero accumulators + class sort (hist/scan/rank+slot) ----
__launch_bounds__(1024)
__global__ void sort_kernel(const int* tg, unsigned int* I, float* out) {
    float* F = (float*)I;
    __shared__ unsigned int h[128], pb[128], cur[128];
    int tid = threadIdx.x;
    for (int e = tid; e < ZERO_F; e += 1024) F[e] = 0.f;
    if (tid == 0) { out[0] = 0.f; out[1] = 0.f; }
    if (tid < 128) { h[tid] = 0; cur[tid] = 0; }
    __syncthreads();
    for (int e = tid; e < Bn; e += 1024) atomicAdd(&h[tg[e]], 1u);
    __syncthreads();
    if (tid < 128) pb[tid] = h[tid] * h[tid];
    __syncthreads();
    for (int s = 1; s < 128; s <<= 1) {
        unsigned int b = 0;
        if (tid < 128 && tid >= s) b = pb[tid - s];
        __syncthreads();
        if (tid < 128) pb[tid] += b;
        __syncthreads();
    }
    if (tid == 127) I[O_P] = pb[127];
    uint2* RM = (uint2*)(I + O_RM);
    for (int e = tid; e < Bn; e += 1024) {
        int c = tg[e];
        unsigned int r = atomicAdd(&cur[c], 1u);
        unsigned int n = h[c];
        RM[e] = make_uint2((unsigned)c | (r << 8), (pb[c] - n * n) + r * n);
    }
}

// ========= R18: 3-z fused + DOUBLE buffer + issue-early/drain-late =========
// R17 post-mortem: 96KB triple-buffer -> 1 blk/CU (1 wave/SIMD, no hiding)
// AND B-panel L2 reuse lost (FETCH 149->295MB). R16's real defect was not
// buffer count but zero load coverage: loads issued at bar#1, drained at
// bar#2 back-to-back. Fix: 2x32KB double buffer (64KB <= 80KB keeps
// 2 blk/CU + L2 reuse) with STAGE of t+1 issued at the TOP of compute-of-t
// -> 48 MFMA + 16 ds_read (~300cy) cover the load latency; ONE
// __syncthreads per K-step (its vmcnt(0) drain is now nearly free).
// Overwrite safety: buf p^1 was last read at kt-1; every wave passed the
// kt-1 barrier before these stage issues (R15-validated consumption proof).
#define BUFS 16384   // shorts per buffer: A[0..4096) B0 B1 B2 (4096 each)

__launch_bounds__(256, 2)
__global__ void gemm_rowsum(const unsigned short* nb, char* ws) {
    float* F = (float*)ws;
    const unsigned int* I = (const unsigned int*)ws;
    const uint2* RM = (const uint2*)(I + O_RM);
    // XCD-aware swizzle (1024 % 8 == 0 -> bijective): 128 consecutive
    // tiles per XCD -> A panels L2-resident, B panels shared by 2 m-rows.
    int bid = blockIdx.x;
    int sw = (bid & 7) * 128 + (bid >> 3);
    int m0 = (sw >> 5) * 128, n0 = (sw & 31) * 128;
    int tid = threadIdx.x, lane = tid & 63, wave = tid >> 6;
    int wm = (wave >> 1) * 64, wn = (wave & 1) * 64;   // 2x2 waves, 64x64/wave/z
    int lid = lane & 15, q = lane >> 4;
    __shared__ __align__(16) unsigned short L[2][BUFS];   // 64 KB

    // staging: thread -> (row = tid>>2, chunk = tid&3); rows 0..63 load0,
    // 64..127 load1 ((row+64)>>1 & 3 unchanged). LDS linear dest,
    // source chunk pre-swizzled (both-sides-or-neither rule).
    int row0 = tid >> 2, ch = tid & 3;
    int cs = (ch ^ ((row0 >> 1) & 3)) * 8;
    const unsigned short* gA  = nb + (size_t)(m0 + row0) * Dd + cs;
    const unsigned short* gB0 = nb + (size_t)(n0 + row0) * Dd + cs;
    const unsigned short* gB1 = gB0 + (size_t)Bn * Dd;
    const unsigned short* gB2 = gB1 + (size_t)Bn * Dd;

    // frag-read swizzle: r = base + i*16 + lid -> (r>>1)&3 == (lid>>1)&3
    int cswz = (q ^ ((lid >> 1) & 3)) * 8;

    f32x4 a0[4][4] = {}, a1[4][4] = {}, a2[4][4] = {};

#define STAGE(b, kt) { \
    const unsigned short* pa  = gA  + (kt) * 32; \
    const unsigned short* pb0 = gB0 + (kt) * 32; \
    const unsigned short* pb1 = gB1 + (kt) * 32; \
    const unsigned short* pb2 = gB2 + (kt) * 32; \
    unsigned short* Lb = L[b]; \
    gl_lds16(pa, &Lb[tid * 8]); \
    gl_lds16(pa + (size_t)64 * Dd, &Lb[(tid + 256) * 8]); \
    gl_lds16(pb0, &Lb[4096 + tid * 8]); \
    gl_lds16(pb0 + (size_t)64 * Dd, &Lb[4096 + (tid + 256) * 8]); \
    gl_lds16(pb1, &Lb[8192 + tid * 8]); \
    gl_lds16(pb1 + (size_t)64 * Dd, &Lb[8192 + (tid + 256) * 8]); \
    gl_lds16(pb2, &Lb[12288 + tid * 8]); \
    gl_lds16(pb2 + (size_t)64 * Dd, &Lb[12288 + (tid + 256) * 8]); \
}

    // prologue: stage t0 -> buf0; publish
    STAGE(0, 0);
    __syncthreads();

    for (int kt = 0; kt < 24; ++kt) {
        int p = kt & 1;
        if (kt < 23) {
            STAGE(p ^ 1, kt + 1);              // issue EARLY: covered by 48 MFMA
            __builtin_amdgcn_sched_barrier(0); // keep issues at the top
        }
        const unsigned short* Lc = L[p];
        sh8 af[4];
        #pragma unroll
        for (int i = 0; i < 4; ++i)
            af[i] = *(const sh8*)&Lc[(wm + i * 16 + lid) * 32 + cswz];
        {
            sh8 bf[4];
            #pragma unroll
            for (int j = 0; j < 4; ++j)
                bf[j] = *(const sh8*)&Lc[4096 + (wn + j * 16 + lid) * 32 + cswz];
            __builtin_amdgcn_s_setprio(1);
            #pragma unroll
            for (int i = 0; i < 4; ++i)
                #pragma unroll
                for (int j = 0; j < 4; ++j)
                    a0[i][j] = __builtin_amdgcn_mfma_f32_16x16x32_bf16(af[i], bf[j], a0[i][j], 0, 0, 0);
            __builtin_amdgcn_s_setprio(0);
        }
        {
            sh8 bf[4];
            #pragma unroll
            for (int j = 0; j < 4; ++j)
                bf[j] = *(const sh8*)&Lc[8192 + (wn + j * 16 + lid) * 32 + cswz];
            __builtin_amdgcn_s_setprio(1);
            #pragma unroll
            for (int i = 0; i < 4; ++i)
                #pragma unroll
                for (int j = 0; j < 4; ++j)
                    a1[i][j] = __builtin_amdgcn_mfma_f32_16x16x32_bf16(af[i], bf[j], a1[i][j], 0, 0, 0);
            __builtin_amdgcn_s_setprio(0);
        }
        {
            sh8 bf[4];
            #pragma unroll
            for (int j = 0; j < 4; ++j)
                bf[j] = *(const sh8*)&Lc[12288 + (wn + j * 16 + lid) * 32 + cswz];
            __builtin_amdgcn_s_setprio(1);
            #pragma unroll
            for (int i = 0; i < 4; ++i)
                #pragma unroll
                for (int j = 0; j < 4; ++j)
                    a2[i][j] = __builtin_amdgcn_mfma_f32_16x16x32_bf16(af[i], bf[j], a2[i][j], 0, 0, 0);
            __builtin_amdgcn_s_setprio(0);
        }
        if (kt < 23) __syncthreads();   // drains vmcnt(0): now covered by compute
    }

    // ---- fused epilogue: 3 row sums, 2 masked sums, single uint4 pair store
    uint2 rmc[4];
    #pragma unroll
    for (int j = 0; j < 4; ++j) rmc[j] = RM[n0 + wn + j * 16 + lid];
    uint4* Lq = (uint4*)(ws + LIST_OFF);
    #pragma unroll
    for (int i = 0; i < 4; ++i)
        #pragma unroll
        for (int reg = 0; reg < 4; ++reg) {
            int grow = m0 + wm + i * 16 + q * 4 + reg;
            uint2 rm = RM[grow];
            unsigned int trow = rm.x & 255u, rsb = rm.y;
            float rs0 = 0.f, rs1 = 0.f, rs2 = 0.f, msOA = 0.f, msG = 0.f;
            #pragma unroll
            for (int j = 0; j < 4; ++j) {
                int gcol = n0 + wn + j * 16 + lid;
                float x0 = a0[i][j][reg] * SC2;
                float x1 = a1[i][j][reg] * SC2;
                float x2 = a2[i][j][reg] * SC2;
                float e0 = exp2f(x0);
                float e1 = exp2f(x1);
                float e2 = exp2f(x2);
                if (gcol == grow) e0 = 0.f;   // ori diagonal excluded from sums
                rs0 += e0; rs1 += e1; rs2 += e2;
                if ((rmc[j].x & 255u) == trow) {
                    msOA += e0 + e2;
                    msG  += e1;
                    unsigned int slot = rsb + (rmc[j].x >> 8);
                    if (slot < LCAP)
                        Lq[slot] = make_uint4((unsigned)grow, __float_as_uint(x0),
                                              __float_as_uint(x1), __float_as_uint(x2));
                }
            }
            #pragma unroll
            for (int off = 1; off < 16; off <<= 1) {
                rs0 += __shfl_xor(rs0, off);
                rs1 += __shfl_xor(rs1, off);
                rs2 += __shfl_xor(rs2, off);
                msOA += __shfl_xor(msOA, off);
                msG  += __shfl_xor(msG, off);
            }
            if (lid == 0) {
                atomicAdd(&F[O_S + grow], rs0);
                atomicAdd(&F[O_S + Bn + grow], rs1);
                atomicAdd(&F[O_S + 2 * Bn + grow], rs2);
                atomicAdd(&F[O_SMOA + grow], msOA);
                atomicAdd(&F[O_SMG + grow], msG);
            }
        }
}

// ---- flat loss pass: inline denominators, scaled atomic into d_out ----
__launch_bounds__(256)
__global__ void loss_kernel(char* ws, float* out) {
    float* F = (float*)ws;
    const unsigned int* I = (const unsigned int*)ws;
    const uint4* L = (const uint4*)(ws + LIST_OFF);
    unsigned int n = I[O_P]; if (n > LCAP) n = LCAP;
    float a0 = 0.f, a1 = 0.f;
    unsigned int stride = gridDim.x * 256;
    for (unsigned int idx = blockIdx.x * 256 + threadIdx.x; idx < n; idx += stride) {
        uint4 en = L[idx];
        int i = (int)en.x;
        float son = F[O_S + i], sgen = F[O_S + Bn + i], saug = F[O_S + 2 * Bn + i];
        float dco = (son + saug - F[O_SMOA + i]) + sgen + EPSF;
        float dad = (sgen - F[O_SMG + i]) + saug + son + DG + EPSF;
        float eo = exp2f(__uint_as_float(en.y));
        float eg = exp2f(__uint_as_float(en.z));
        float ea = exp2f(__uint_as_float(en.w));
        a0 += -__logf(eg / (eg + dad) + EPSF);
        a1 += -__logf(eo / (eo + dco) + EPSF) - __logf(ea / (ea + dco) + EPSF);
    }
    #pragma unroll
    for (int off = 1; off < 64; off <<= 1) { a0 += __shfl_xor(a0, off); a1 += __shfl_xor(a1, off); }
    __shared__ float r0[4], r1[4];
    int tid = threadIdx.x;
    if ((tid & 63) == 0) { r0[tid >> 6] = a0; r1[tid >> 6] = a1; }
    __syncthreads();
    if (tid == 0) {
        atomicAdd(&out[0], (r0[0] + r0[1] + r0[2] + r0[3]) * (1.0f / Bn));  // ad_loss
        atomicAdd(&out[1], (r1[0] + r1[1] + r1[2] + r1[3]) * (1.0f / Bn));  // co_loss
    }
}

extern "C" void kernel_launch(void* const* d_in, const int* in_sizes, int n_in,
                              void* d_out, int out_size, void* d_ws, size_t ws_size,
                              hipStream_t stream) {
    const float* f0 = (const float*)d_in[0];
    const float* f1 = (const float*)d_in[1];
    const float* f2 = (const float*)d_in[2];
    const int* tg = (const int*)d_in[3];
    char* ws = (char*)d_ws;
    unsigned int* I = (unsigned int*)d_ws;
    unsigned short* nb = (unsigned short*)(ws + NB_OFF);
    float* out = (float*)d_out;

    norm_kernel<<<dim3(Bn, 3), 256, 0, stream>>>(f0, f1, f2, nb);
    sort_kernel<<<1, 1024, 0, stream>>>(tg, I, out);
    gemm_rowsum<<<dim3(1024), 256, 0, stream>>>(nb, ws);
    loss_kernel<<<256, 256, 0, stream>>>(ws, out);
}

// Round 6
// 201.466 us; speedup vs baseline: 1.2408x; 1.0504x over previous
//
#include <hip/hip_runtime.h>
#include <hip/hip_bf16.h>
#include <math.h>

#define Bn 4096
#define Dd 768
#define SC2 28.85390081777927f   // 20 * log2(e): logits kept in base-2 domain
#define EPSF 1e-6f
#define DG 4.8516519541e8f       // expf(20.0f): exact exp_ori diagonal

// ws layout (4-byte elements)
#define O_S      0        // 3*4096 row sums (ori_nodiag, gen, aug)
#define O_SMOA   12288    // same-masked (ori_nodiag + aug) sums
#define O_SMG    16384    // same-masked gen sums
#define ZERO_F   20480    // floats to zero (covers all atomic sums)
#define O_P      20480    // uint: total pairs (= sum cnt^2)
#define O_RM     20608    // uint2[4096]: {tg | rank<<8, rowSlotBase}
#define LIST_OFF   262144      // byte offset: LCAP uint4 pair entries {row,x0,x1,x2}
#define LCAP       (1u << 19)
#define NB_OFF     33554432    // byte offset: bf16 normalized rows on|gn|an

typedef __attribute__((ext_vector_type(8))) short sh8;
typedef __attribute__((ext_vector_type(4))) float f32x4;

#define AS1 __attribute__((address_space(1)))
#define AS3 __attribute__((address_space(3)))

static __device__ __forceinline__ void gl_lds16(const void* g, void* l) {
    __builtin_amdgcn_global_load_lds((const AS1 void*)g, (AS3 void*)l, 16, 0, 0);
}

static __device__ __forceinline__ unsigned short f2b(float f) {
    unsigned int u = __float_as_uint(f);
    unsigned int r = (u + 0x7fffu + ((u >> 16) & 1u)) >> 16;  // RNE
    return (unsigned short)r;
}

// ---- normalize rows (blocks x<4096) + class sort (block x==4096,y==0) ----
// Fused to save one kernel dispatch: sort work is independent of norm work
// and only needs tg; it runs concurrently with the 12288 norm blocks.
__global__ void norm_sort_kernel(const float* f0, const float* f1, const float* f2,
                                 unsigned short* nb, const int* tg, unsigned int* I,
                                 float* out) {
    int r = blockIdx.x, m = blockIdx.y, tid = threadIdx.x;
    if (r == Bn) {
        if (m != 0) return;
        // ---- sort body (256 threads) ----
        float* F = (float*)I;
        __shared__ unsigned int h[128], pb[128], cur[128];
        for (int e = tid; e < ZERO_F; e += 256) F[e] = 0.f;
        if (tid == 0) { out[0] = 0.f; out[1] = 0.f; }
        if (tid < 128) { h[tid] = 0; cur[tid] = 0; }
        __syncthreads();
        for (int e = tid; e < Bn; e += 256) atomicAdd(&h[tg[e]], 1u);
        __syncthreads();
        if (tid < 128) pb[tid] = h[tid] * h[tid];
        __syncthreads();
        for (int s = 1; s < 128; s <<= 1) {
            unsigned int b = 0;
            if (tid < 128 && tid >= s) b = pb[tid - s];
            __syncthreads();
            if (tid < 128) pb[tid] += b;
            __syncthreads();
        }
        if (tid == 127) I[O_P] = pb[127];
        uint2* RM = (uint2*)(I + O_RM);
        for (int e = tid; e < Bn; e += 256) {
            int c = tg[e];
            unsigned int rk = atomicAdd(&cur[c], 1u);
            unsigned int n = h[c];
            RM[e] = make_uint2((unsigned)c | (rk << 8), (pb[c] - n * n) + rk * n);
        }
        return;
    }
    const float* src = (m == 0 ? f0 : (m == 1 ? f1 : f2)) + (size_t)r * Dd;
    float x0 = src[tid], x1 = src[tid + 256], x2 = src[tid + 512];
    float v = x0 * x0 + x1 * x1 + x2 * x2;
    #pragma unroll
    for (int off = 1; off < 64; off <<= 1) v += __shfl_xor(v, off);
    __shared__ float wr[4];
    if ((tid & 63) == 0) wr[tid >> 6] = v;
    __syncthreads();
    float inv = rsqrtf(wr[0] + wr[1] + wr[2] + wr[3]);
    unsigned short* dst = nb + ((size_t)m * Bn + r) * Dd;
    dst[tid] = f2b(x0 * inv);
    dst[tid + 256] = f2b(x1 * inv);
    dst[tid + 512] = f2b(x2 * inv);
}

// ============ R19: R16 skeleton + z-staged reads + n-owned XCD tiles =======
// R16 (116us, MfmaUtil 27.7%, FETCH 149MB) is the proven best structure:
// 32KB single buffer keeps 3+ blocks/CU resident (the thing R14/R15/R17/R18
// all sacrificed and lost). Two additions, both residency-neutral:
// (a) z-staged read interleave: pin {af+bf0+bf1 reads} / MFMA-z0 /
//     {bf2 reads} / MFMA-z1 / MFMA-z2 with sched_barrier(0). First-MFMA
//     now gates on 8 ds_reads instead of 16; bf2 reads land under z0 MFMAs.
// (b) n-owned XCD supertile: XCD x owns n-panels {4x..4x+3} x all 32 m,
//     n-inner order -> per-XCD B working set 2.35MB (fits 4MB L2, was
//     18.9MB = whole B). Ideal FETCH = 8*(6.3A + 2.35B) = 69MB (was 149).
__launch_bounds__(256, 2)
__global__ void gemm_rowsum(const unsigned short* nb, char* ws) {
    float* F = (float*)ws;
    const unsigned int* I = (const unsigned int*)ws;
    const uint2* RM = (const uint2*)(I + O_RM);
    int bid = blockIdx.x;
    int xcd = bid & 7, local = bid >> 3;                // 8 XCDs x 128 tiles
    int n0 = (xcd * 4 + (local & 3)) * 128;             // 4 n-panels per XCD
    int m0 = (local >> 2) * 128;                        // n-inner, m-major
    int tid = threadIdx.x, lane = tid & 63, wave = tid >> 6;
    int wm = (wave >> 1) * 64, wn = (wave & 1) * 64;    // 2x2 waves, 64x64/wave/z
    int lid = lane & 15, q = lane >> 4;
    __shared__ __align__(16) unsigned short Asm[128 * 32];      // 8 KB
    __shared__ __align__(16) unsigned short Bsm[3][128 * 32];   // 24 KB

    // staging: thread -> (row = tid>>2, chunk = tid&3); rows 0..63 load0,
    // 64..127 load1 ((row+64)>>1 & 3 unchanged). LDS linear dest,
    // source chunk pre-swizzled (both-sides-or-neither rule).
    int row0 = tid >> 2, ch = tid & 3;
    int cs = (ch ^ ((row0 >> 1) & 3)) * 8;
    const unsigned short* gA  = nb + (size_t)(m0 + row0) * Dd + cs;
    const unsigned short* gB0 = nb + (size_t)(n0 + row0) * Dd + cs;
    const unsigned short* gB1 = gB0 + (size_t)Bn * Dd;
    const unsigned short* gB2 = gB1 + (size_t)Bn * Dd;
    unsigned short* lA0 = &Asm[tid * 8];
    unsigned short* lA1 = &Asm[(tid + 256) * 8];

    // frag-read swizzle: r = base + i*16 + lid -> (r>>1)&3 == (lid>>1)&3
    int cswz = (q ^ ((lid >> 1) & 3)) * 8;

    f32x4 a0[4][4] = {}, a1[4][4] = {}, a2[4][4] = {};

    for (int kt = 0; kt < 24; ++kt) {
        const unsigned short* pa  = gA  + kt * 32;
        const unsigned short* pb0 = gB0 + kt * 32;
        const unsigned short* pb1 = gB1 + kt * 32;
        const unsigned short* pb2 = gB2 + kt * 32;
        __syncthreads();
        gl_lds16(pa, lA0);
        gl_lds16(pa + (size_t)64 * Dd, lA1);
        gl_lds16(pb0, &Bsm[0][tid * 8]);
        gl_lds16(pb0 + (size_t)64 * Dd, &Bsm[0][(tid + 256) * 8]);
        gl_lds16(pb1, &Bsm[1][tid * 8]);
        gl_lds16(pb1 + (size_t)64 * Dd, &Bsm[1][(tid + 256) * 8]);
        gl_lds16(pb2, &Bsm[2][tid * 8]);
        gl_lds16(pb2 + (size_t)64 * Dd, &Bsm[2][(tid + 256) * 8]);
        __syncthreads();
        // ---- z-staged reads: af+bf0+bf1 now, bf2 under z0's MFMAs ----
        sh8 af[4], bf0[4], bf1[4], bf2[4];
        #pragma unroll
        for (int i = 0; i < 4; ++i)
            af[i] = *(const sh8*)&Asm[(wm + i * 16 + lid) * 32 + cswz];
        #pragma unroll
        for (int j = 0; j < 4; ++j)
            bf0[j] = *(const sh8*)&Bsm[0][(wn + j * 16 + lid) * 32 + cswz];
        #pragma unroll
        for (int j = 0; j < 4; ++j)
            bf1[j] = *(const sh8*)&Bsm[1][(wn + j * 16 + lid) * 32 + cswz];
        __builtin_amdgcn_sched_barrier(0);
        __builtin_amdgcn_s_setprio(1);
        #pragma unroll
        for (int i = 0; i < 4; ++i)
            #pragma unroll
            for (int j = 0; j < 4; ++j)
                a0[i][j] = __builtin_amdgcn_mfma_f32_16x16x32_bf16(af[i], bf0[j], a0[i][j], 0, 0, 0);
        __builtin_amdgcn_s_setprio(0);
        __builtin_amdgcn_sched_barrier(0);
        #pragma unroll
        for (int j = 0; j < 4; ++j)
            bf2[j] = *(const sh8*)&Bsm[2][(wn + j * 16 + lid) * 32 + cswz];
        __builtin_amdgcn_sched_barrier(0);
        __builtin_amdgcn_s_setprio(1);
        #pragma unroll
        for (int i = 0; i < 4; ++i)
            #pragma unroll
            for (int j = 0; j < 4; ++j)
                a1[i][j] = __builtin_amdgcn_mfma_f32_16x16x32_bf16(af[i], bf1[j], a1[i][j], 0, 0, 0);
        __builtin_amdgcn_s_setprio(0);
        __builtin_amdgcn_sched_barrier(0);
        __builtin_amdgcn_s_setprio(1);
        #pragma unroll
        for (int i = 0; i < 4; ++i)
            #pragma unroll
            for (int j = 0; j < 4; ++j)
                a2[i][j] = __builtin_amdgcn_mfma_f32_16x16x32_bf16(af[i], bf2[j], a2[i][j], 0, 0, 0);
        __builtin_amdgcn_s_setprio(0);
    }

    // ---- fused epilogue: 3 row sums, 2 masked sums, single uint4 pair store
    uint2 rmc[4];
    #pragma unroll
    for (int j = 0; j < 4; ++j) rmc[j] = RM[n0 + wn + j * 16 + lid];
    uint4* Lq = (uint4*)(ws + LIST_OFF);
    #pragma unroll
    for (int i = 0; i < 4; ++i)
        #pragma unroll
        for (int reg = 0; reg < 4; ++reg) {
            int grow = m0 + wm + i * 16 + q * 4 + reg;
            uint2 rm = RM[grow];
            unsigned int trow = rm.x & 255u, rsb = rm.y;
            float rs0 = 0.f, rs1 = 0.f, rs2 = 0.f, msOA = 0.f, msG = 0.f;
            #pragma unroll
            for (int j = 0; j < 4; ++j) {
                int gcol = n0 + wn + j * 16 + lid;
                float x0 = a0[i][j][reg] * SC2;
                float x1 = a1[i][j][reg] * SC2;
                float x2 = a2[i][j][reg] * SC2;
                float e0 = exp2f(x0);
                float e1 = exp2f(x1);
                float e2 = exp2f(x2);
                if (gcol == grow) e0 = 0.f;   // ori diagonal excluded from sums
                rs0 += e0; rs1 += e1; rs2 += e2;
                if ((rmc[j].x & 255u) == trow) {
                    msOA += e0 + e2;
                    msG  += e1;
                    unsigned int slot = rsb + (rmc[j].x >> 8);
                    if (slot < LCAP)
                        Lq[slot] = make_uint4((unsigned)grow, __float_as_uint(x0),
                                              __float_as_uint(x1), __float_as_uint(x2));
                }
            }
            #pragma unroll
            for (int off = 1; off < 16; off <<= 1) {
                rs0 += __shfl_xor(rs0, off);
                rs1 += __shfl_xor(rs1, off);
                rs2 += __shfl_xor(rs2, off);
                msOA += __shfl_xor(msOA, off);
                msG  += __shfl_xor(msG, off);
            }
            if (lid == 0) {
                atomicAdd(&F[O_S + grow], rs0);
                atomicAdd(&F[O_S + Bn + grow], rs1);
                atomicAdd(&F[O_S + 2 * Bn + grow], rs2);
                atomicAdd(&F[O_SMOA + grow], msOA);
                atomicAdd(&F[O_SMG + grow], msG);
            }
        }
}

// ---- flat loss pass: inline denominators, scaled atomic into d_out ----
__launch_bounds__(256)
__global__ void loss_kernel(char* ws, float* out) {
    float* F = (float*)ws;
    const unsigned int* I = (const unsigned int*)ws;
    const uint4* L = (const uint4*)(ws + LIST_OFF);
    unsigned int n = I[O_P]; if (n > LCAP) n = LCAP;
    float a0 = 0.f, a1 = 0.f;
    unsigned int stride = gridDim.x * 256;
    for (unsigned int idx = blockIdx.x * 256 + threadIdx.x; idx < n; idx += stride) {
        uint4 en = L[idx];
        int i = (int)en.x;
        float son = F[O_S + i], sgen = F[O_S + Bn + i], saug = F[O_S + 2 * Bn + i];
        float dco = (son + saug - F[O_SMOA + i]) + sgen + EPSF;
        float dad = (sgen - F[O_SMG + i]) + saug + son + DG + EPSF;
        float eo = exp2f(__uint_as_float(en.y));
        float eg = exp2f(__uint_as_float(en.z));
        float ea = exp2f(__uint_as_float(en.w));
        a0 += -__logf(eg / (eg + dad) + EPSF);
        a1 += -__logf(eo / (eo + dco) + EPSF) - __logf(ea / (ea + dco) + EPSF);
    }
    #pragma unroll
    for (int off = 1; off < 64; off <<= 1) { a0 += __shfl_xor(a0, off); a1 += __shfl_xor(a1, off); }
    __shared__ float r0[4], r1[4];
    int tid = threadIdx.x;
    if ((tid & 63) == 0) { r0[tid >> 6] = a0; r1[tid >> 6] = a1; }
    __syncthreads();
    if (tid == 0) {
        atomicAdd(&out[0], (r0[0] + r0[1] + r0[2] + r0[3]) * (1.0f / Bn));  // ad_loss
        atomicAdd(&out[1], (r1[0] + r1[1] + r1[2] + r1[3]) * (1.0f / Bn));  // co_loss
    }
}

extern "C" void kernel_launch(void* const* d_in, const int* in_sizes, int n_in,
                              void* d_out, int out_size, void* d_ws, size_t ws_size,
                              hipStream_t stream) {
    const float* f0 = (const float*)d_in[0];
    const float* f1 = (const float*)d_in[1];
    const float* f2 = (const float*)d_in[2];
    const int* tg = (const int*)d_in[3];
    char* ws = (char*)d_ws;
    unsigned int* I = (unsigned int*)d_ws;
    unsigned short* nb = (unsigned short*)(ws + NB_OFF);
    float* out = (float*)d_out;

    norm_sort_kernel<<<dim3(Bn + 1, 3), 256, 0, stream>>>(f0, f1, f2, nb, tg, I, out);
    gemm_rowsum<<<dim3(1024), 256, 0, stream>>>(nb, ws);
    loss_kernel<<<256, 256, 0, stream>>>(ws, out);
}

// Round 7
// 200.119 us; speedup vs baseline: 1.2492x; 1.0067x over previous
//
#include <hip/hip_runtime.h>
#include <hip/hip_bf16.h>
#include <math.h>

#define Bn 4096
#define Dd 768
#define SC2 28.85390081777927f   // 20 * log2(e): logits kept in base-2 domain
#define EPSF 1e-6f
#define DG 4.8516519541e8f       // expf(20.0f): exact exp_ori diagonal

// ws layout (4-byte elements)
#define O_S      0        // 3*4096 row sums (ori_nodiag, gen, aug)
#define O_SMOA   12288    // same-masked (ori_nodiag + aug) sums
#define O_SMG    16384    // same-masked gen sums
#define ZERO_F   20480    // floats to zero (covers all atomic sums)
#define O_P      20480    // uint: total pairs (= sum cnt^2)
#define O_RM     20608    // uint2[4096]: {tg | rank<<8, rowSlotBase}
#define LIST_OFF   262144      // byte offset: LCAP uint4 pair entries {row,x0,x1,x2}
#define LCAP       (1u << 19)
#define NB_OFF     33554432    // byte offset: bf16 normalized rows on|gn|an

typedef __attribute__((ext_vector_type(8))) short sh8;
typedef __attribute__((ext_vector_type(4))) float f32x4;

#define AS1 __attribute__((address_space(1)))
#define AS3 __attribute__((address_space(3)))

static __device__ __forceinline__ void gl_lds16(const void* g, void* l) {
    __builtin_amdgcn_global_load_lds((const AS1 void*)g, (AS3 void*)l, 16, 0, 0);
}

static __device__ __forceinline__ unsigned short f2b(float f) {
    unsigned int u = __float_as_uint(f);
    unsigned int r = (u + 0x7fffu + ((u >> 16) & 1u)) >> 16;  // RNE
    return (unsigned short)r;
}

// ---- normalize rows (blocks x<4096) + class sort (block x==4096,y==0) ----
__global__ void norm_sort_kernel(const float* f0, const float* f1, const float* f2,
                                 unsigned short* nb, const int* tg, unsigned int* I,
                                 float* out) {
    int r = blockIdx.x, m = blockIdx.y, tid = threadIdx.x;
    if (r == Bn) {
        if (m != 0) return;
        // ---- sort body (256 threads) ----
        float* F = (float*)I;
        __shared__ unsigned int h[128], pb[128], cur[128];
        for (int e = tid; e < ZERO_F; e += 256) F[e] = 0.f;
        if (tid == 0) { out[0] = 0.f; out[1] = 0.f; }
        if (tid < 128) { h[tid] = 0; cur[tid] = 0; }
        __syncthreads();
        for (int e = tid; e < Bn; e += 256) atomicAdd(&h[tg[e]], 1u);
        __syncthreads();
        if (tid < 128) pb[tid] = h[tid] * h[tid];
        __syncthreads();
        for (int s = 1; s < 128; s <<= 1) {
            unsigned int b = 0;
            if (tid < 128 && tid >= s) b = pb[tid - s];
            __syncthreads();
            if (tid < 128) pb[tid] += b;
            __syncthreads();
        }
        if (tid == 127) I[O_P] = pb[127];
        uint2* RM = (uint2*)(I + O_RM);
        for (int e = tid; e < Bn; e += 256) {
            int c = tg[e];
            unsigned int rk = atomicAdd(&cur[c], 1u);
            unsigned int n = h[c];
            RM[e] = make_uint2((unsigned)c | (rk << 8), (pb[c] - n * n) + rk * n);
        }
        return;
    }
    const float* src = (m == 0 ? f0 : (m == 1 ? f1 : f2)) + (size_t)r * Dd;
    float x0 = src[tid], x1 = src[tid + 256], x2 = src[tid + 512];
    float v = x0 * x0 + x1 * x1 + x2 * x2;
    #pragma unroll
    for (int off = 1; off < 64; off <<= 1) v += __shfl_xor(v, off);
    __shared__ float wr[4];
    if ((tid & 63) == 0) wr[tid >> 6] = v;
    __syncthreads();
    float inv = rsqrtf(wr[0] + wr[1] + wr[2] + wr[3]);
    unsigned short* dst = nb + ((size_t)m * Bn + r) * Dd;
    dst[tid] = f2b(x0 * inv);
    dst[tid + 256] = f2b(x1 * inv);
    dst[tid + 512] = f2b(x2 * inv);
}

// ===== R20: R19 (n-owned XCD, z-staged reads) + double-buffer issue-early ==
// R19 proved fetch is solved (40.5MB ~= ideal 37.8) and exposed the real
// stall: R16/R19 issue the 8 gl_lds between two BACK-TO-BACK barriers, so
// barrier#2's vmcnt(0) drain eats the full L2/L3 latency every K-step with
// nothing in flight. Single change this round (clean A/B vs R19): 2x32KB
// double buffer; STAGE(t+1 -> buf p^1) issued at the TOP of compute-of-t;
// ONE __syncthreads per K-step at the bottom. The ~1900cy of ds_read+MFMA
// covers the load latency, so the bottom drain is nearly free. Overwrite
// safety: buf p^1 was last read at kt-1 and all waves passed the kt-1
// bottom barrier before the stage issues (validated by R15/R18 absmax 0).
// Residency unchanged: 64KB LDS still allows 2 blk/CU; regs gate at 2
// (R18 measured 20.7% occupancy at this exact footprint).
__launch_bounds__(256, 2)
__global__ void gemm_rowsum(const unsigned short* nb, char* ws) {
    float* F = (float*)ws;
    const unsigned int* I = (const unsigned int*)ws;
    const uint2* RM = (const uint2*)(I + O_RM);
    int bid = blockIdx.x;
    int xcd = bid & 7, local = bid >> 3;                // 8 XCDs x 128 tiles
    int n0 = (xcd * 4 + (local & 3)) * 128;             // 4 n-panels per XCD (B L2-resident)
    int m0 = (local >> 2) * 128;                        // n-inner, m-major
    int tid = threadIdx.x, lane = tid & 63, wave = tid >> 6;
    int wm = (wave >> 1) * 64, wn = (wave & 1) * 64;    // 2x2 waves, 64x64/wave/z
    int lid = lane & 15, q = lane >> 4;
    __shared__ __align__(16) unsigned short L[2][4][128 * 32];  // 2 bufs x {A,B0,B1,B2}

    // staging: thread -> (row = tid>>2, chunk = tid&3); rows 0..63 load0,
    // 64..127 load1 ((row+64)>>1 & 3 unchanged). LDS linear dest,
    // source chunk pre-swizzled (both-sides-or-neither rule).
    int row0 = tid >> 2, ch = tid & 3;
    int cs = (ch ^ ((row0 >> 1) & 3)) * 8;
    const unsigned short* gA  = nb + (size_t)(m0 + row0) * Dd + cs;
    const unsigned short* gB0 = nb + (size_t)(n0 + row0) * Dd + cs;
    const unsigned short* gB1 = gB0 + (size_t)Bn * Dd;
    const unsigned short* gB2 = gB1 + (size_t)Bn * Dd;

    // frag-read swizzle: r = base + i*16 + lid -> (r>>1)&3 == (lid>>1)&3
    int cswz = (q ^ ((lid >> 1) & 3)) * 8;

    f32x4 a0[4][4] = {}, a1[4][4] = {}, a2[4][4] = {};

#define STAGE(b, kt) { \
    const unsigned short* pa  = gA  + (kt) * 32; \
    const unsigned short* pb0 = gB0 + (kt) * 32; \
    const unsigned short* pb1 = gB1 + (kt) * 32; \
    const unsigned short* pb2 = gB2 + (kt) * 32; \
    gl_lds16(pa, &L[b][0][tid * 8]); \
    gl_lds16(pa + (size_t)64 * Dd, &L[b][0][(tid + 256) * 8]); \
    gl_lds16(pb0, &L[b][1][tid * 8]); \
    gl_lds16(pb0 + (size_t)64 * Dd, &L[b][1][(tid + 256) * 8]); \
    gl_lds16(pb1, &L[b][2][tid * 8]); \
    gl_lds16(pb1 + (size_t)64 * Dd, &L[b][2][(tid + 256) * 8]); \
    gl_lds16(pb2, &L[b][3][tid * 8]); \
    gl_lds16(pb2 + (size_t)64 * Dd, &L[b][3][(tid + 256) * 8]); \
}

    // prologue: stage t0 -> buf0; publish (one exposed drain, once)
    STAGE(0, 0);
    __syncthreads();

    for (int kt = 0; kt < 24; ++kt) {
        int p = kt & 1;
        if (kt < 23) {
            STAGE(p ^ 1, kt + 1);              // issue EARLY: covered by reads+MFMA
            __builtin_amdgcn_sched_barrier(0); // keep issues at the top
        }
        // ---- z-staged reads: af+bf0+bf1 now, bf2 under z0's MFMAs ----
        sh8 af[4], bf0[4], bf1[4], bf2[4];
        #pragma unroll
        for (int i = 0; i < 4; ++i)
            af[i] = *(const sh8*)&L[p][0][(wm + i * 16 + lid) * 32 + cswz];
        #pragma unroll
        for (int j = 0; j < 4; ++j)
            bf0[j] = *(const sh8*)&L[p][1][(wn + j * 16 + lid) * 32 + cswz];
        #pragma unroll
        for (int j = 0; j < 4; ++j)
            bf1[j] = *(const sh8*)&L[p][2][(wn + j * 16 + lid) * 32 + cswz];
        __builtin_amdgcn_sched_barrier(0);
        __builtin_amdgcn_s_setprio(1);
        #pragma unroll
        for (int i = 0; i < 4; ++i)
            #pragma unroll
            for (int j = 0; j < 4; ++j)
                a0[i][j] = __builtin_amdgcn_mfma_f32_16x16x32_bf16(af[i], bf0[j], a0[i][j], 0, 0, 0);
        __builtin_amdgcn_s_setprio(0);
        __builtin_amdgcn_sched_barrier(0);
        #pragma unroll
        for (int j = 0; j < 4; ++j)
            bf2[j] = *(const sh8*)&L[p][3][(wn + j * 16 + lid) * 32 + cswz];
        __builtin_amdgcn_sched_barrier(0);
        __builtin_amdgcn_s_setprio(1);
        #pragma unroll
        for (int i = 0; i < 4; ++i)
            #pragma unroll
            for (int j = 0; j < 4; ++j)
                a1[i][j] = __builtin_amdgcn_mfma_f32_16x16x32_bf16(af[i], bf1[j], a1[i][j], 0, 0, 0);
        __builtin_amdgcn_s_setprio(0);
        __builtin_amdgcn_sched_barrier(0);
        __builtin_amdgcn_s_setprio(1);
        #pragma unroll
        for (int i = 0; i < 4; ++i)
            #pragma unroll
            for (int j = 0; j < 4; ++j)
                a2[i][j] = __builtin_amdgcn_mfma_f32_16x16x32_bf16(af[i], bf2[j], a2[i][j], 0, 0, 0);
        __builtin_amdgcn_s_setprio(0);
        if (kt < 23) __syncthreads();   // bottom drain: loads had ~1900cy coverage
    }

    // ---- fused epilogue: 3 row sums, 2 masked sums, single uint4 pair store
    uint2 rmc[4];
    #pragma unroll
    for (int j = 0; j < 4; ++j) rmc[j] = RM[n0 + wn + j * 16 + lid];
    uint4* Lq = (uint4*)(ws + LIST_OFF);
    #pragma unroll
    for (int i = 0; i < 4; ++i)
        #pragma unroll
        for (int reg = 0; reg < 4; ++reg) {
            int grow = m0 + wm + i * 16 + q * 4 + reg;
            uint2 rm = RM[grow];
            unsigned int trow = rm.x & 255u, rsb = rm.y;
            float rs0 = 0.f, rs1 = 0.f, rs2 = 0.f, msOA = 0.f, msG = 0.f;
            #pragma unroll
            for (int j = 0; j < 4; ++j) {
                int gcol = n0 + wn + j * 16 + lid;
                float x0 = a0[i][j][reg] * SC2;
                float x1 = a1[i][j][reg] * SC2;
                float x2 = a2[i][j][reg] * SC2;
                float e0 = exp2f(x0);
                float e1 = exp2f(x1);
                float e2 = exp2f(x2);
                if (gcol == grow) e0 = 0.f;   // ori diagonal excluded from sums
                rs0 += e0; rs1 += e1; rs2 += e2;
                if ((rmc[j].x & 255u) == trow) {
                    msOA += e0 + e2;
                    msG  += e1;
                    unsigned int slot = rsb + (rmc[j].x >> 8);
                    if (slot < LCAP)
                        Lq[slot] = make_uint4((unsigned)grow, __float_as_uint(x0),
                                              __float_as_uint(x1), __float_as_uint(x2));
                }
            }
            #pragma unroll
            for (int off = 1; off < 16; off <<= 1) {
                rs0 += __shfl_xor(rs0, off);
                rs1 += __shfl_xor(rs1, off);
                rs2 += __shfl_xor(rs2, off);
                msOA += __shfl_xor(msOA, off);
                msG  += __shfl_xor(msG, off);
            }
            if (lid == 0) {
                atomicAdd(&F[O_S + grow], rs0);
                atomicAdd(&F[O_S + Bn + grow], rs1);
                atomicAdd(&F[O_S + 2 * Bn + grow], rs2);
                atomicAdd(&F[O_SMOA + grow], msOA);
                atomicAdd(&F[O_SMG + grow], msG);
            }
        }
}

// ---- flat loss pass: inline denominators, scaled atomic into d_out ----
__launch_bounds__(256)
__global__ void loss_kernel(char* ws, float* out) {
    float* F = (float*)ws;
    const unsigned int* I = (const unsigned int*)ws;
    const uint4* L = (const uint4*)(ws + LIST_OFF);
    unsigned int n = I[O_P]; if (n > LCAP) n = LCAP;
    float a0 = 0.f, a1 = 0.f;
    unsigned int stride = gridDim.x * 256;
    for (unsigned int idx = blockIdx.x * 256 + threadIdx.x; idx < n; idx += stride) {
        uint4 en = L[idx];
        int i = (int)en.x;
        float son = F[O_S + i], sgen = F[O_S + Bn + i], saug = F[O_S + 2 * Bn + i];
        float dco = (son + saug - F[O_SMOA + i]) + sgen + EPSF;
        float dad = (sgen - F[O_SMG + i]) + saug + son + DG + EPSF;
        float eo = exp2f(__uint_as_float(en.y));
        float eg = exp2f(__uint_as_float(en.z));
        float ea = exp2f(__uint_as_float(en.w));
        a0 += -__logf(eg / (eg + dad) + EPSF);
        a1 += -__logf(eo / (eo + dco) + EPSF) - __logf(ea / (ea + dco) + EPSF);
    }
    #pragma unroll
    for (int off = 1; off < 64; off <<= 1) { a0 += __shfl_xor(a0, off); a1 += __shfl_xor(a1, off); }
    __shared__ float r0[4], r1[4];
    int tid = threadIdx.x;
    if ((tid & 63) == 0) { r0[tid >> 6] = a0; r1[tid >> 6] = a1; }
    __syncthreads();
    if (tid == 0) {
        atomicAdd(&out[0], (r0[0] + r0[1] + r0[2] + r0[3]) * (1.0f / Bn));  // ad_loss
        atomicAdd(&out[1], (r1[0] + r1[1] + r1[2] + r1[3]) * (1.0f / Bn));  // co_loss
    }
}

extern "C" void kernel_launch(void* const* d_in, const int* in_sizes, int n_in,
                              void* d_out, int out_size, void* d_ws, size_t ws_size,
                              hipStream_t stream) {
    const float* f0 = (const float*)d_in[0];
    const float* f1 = (const float*)d_in[1];
    const float* f2 = (const float*)d_in[2];
    const int* tg = (const int*)d_in[3];
    char* ws = (char*)d_ws;
    unsigned int* I = (unsigned int*)d_ws;
    unsigned short* nb = (unsigned short*)(ws + NB_OFF);
    float* out = (float*)d_out;

    norm_sort_kernel<<<dim3(Bn + 1, 3), 256, 0, stream>>>(f0, f1, f2, nb, tg, I, out);
    gemm_rowsum<<<dim3(1024), 256, 0, stream>>>(nb, ws);
    loss_kernel<<<256, 256, 0, stream>>>(ws, out);
}